// Round 1
// baseline (358.045 us; speedup 1.0000x reference)
//
#include <hip/hip_runtime.h>

#define IN_F   360
#define HIDN   64
#define NCLS   5
#define BATCH  64
#define SEQ    128
#define NROWS  (BATCH*SEQ)   // 8192

// workspace layout (float offsets). total ~15.2 MB
#define WS_WPACK 0           // float4[360*64]  = 92160 floats
#define WS_WT4   92160       // 24576 floats  (w_ih transposed, float4-packed)
#define WS_XEMB  116736      // 8192*64 = 524288
#define WS_GI    641024      // 8192*384 = 3145728
#define WS_HC    3786752     // 64*128 = 8192

__device__ __forceinline__ float fast_rcp(float x) { return __builtin_amdgcn_rcpf(x); }
__device__ __forceinline__ float fast_rsq(float x) { return __builtin_amdgcn_rsqf(x); }
__device__ __forceinline__ float sigmoid_(float x) {
    x = fminf(fmaxf(x, -60.0f), 60.0f);
    return fast_rcp(1.0f + exp2f(-1.4426950408889634f * x));
}
__device__ __forceinline__ float tanh_(float x) {
    x = fminf(fmaxf(x, -30.0f), 30.0f);
    float e = exp2f(-2.8853900817779268f * x);   // e^{-2x}
    return (1.0f - e) * fast_rcp(1.0f + e);
}

// ---------------- K0: weight prep ----------------
// wpack[i*64+o] = {1/s, -t/s, MH_CONST*w, base_w}  (transposed for coalesced o-lane reads)
// wT4[(k4*384+g)*4+e] = w_ih_{dir}[gg][k4*4+e], g = dir*192+gg
__global__ __launch_bounds__(256) void prep_kernel(
    const float* __restrict__ scale, const float* __restrict__ trans,
    const float* __restrict__ ww,    const float* __restrict__ bw,
    const float* __restrict__ wihf,  const float* __restrict__ wihb,
    float* __restrict__ ws) {
    int idx = blockIdx.x * 256 + threadIdx.x;
    float4* wpack = (float4*)(ws + WS_WPACK);
    float*  wT4   = ws + WS_WT4;
    if (idx < 64 * IN_F) {
        int o = idx & 63, i = idx >> 6;
        float a  = 1.0f / scale[o * IN_F + i];
        float b  = -trans[o * IN_F + i] * a;
        float wq = 0.8673250705840776f * ww[o * IN_F + i];   // 2/(sqrt(3)*pi^0.25)
        float bb = bw[o * IN_F + i];
        wpack[i * 64 + o] = make_float4(a, b, wq, bb);
    }
    int idx2 = idx - 64 * IN_F;
    if (idx2 >= 0 && idx2 < 24576) {
        int e = idx2 & 3; int rest = idx2 >> 2;
        int g = rest % 384; int k4 = rest / 384;
        int k = k4 * 4 + e; int dir = g / 192; int gg = g - dir * 192;
        const float* src = dir ? wihb : wihf;
        wT4[idx2] = src[gg * 64 + k];
    }
}

// ---------------- K1: WavKAN + BatchNorm + LayerNorm ----------------
// block = 256 thr (4 waves), 16 rows/block. lane = o (0..63), wave grp owns 4 rows.
__global__ __launch_bounds__(256) void wavkan_kernel(
    const float* __restrict__ x_seq,
    const float* __restrict__ bn_g, const float* __restrict__ bn_b,
    const float* __restrict__ bn_m, const float* __restrict__ bn_v,
    const float* __restrict__ ln_g, const float* __restrict__ ln_b,
    const float* __restrict__ ws_c, float* __restrict__ x_emb) {
    __shared__ float2 xs_lds[16 * IN_F];   // {x, silu(x)} per (row,i) : 46 KB
    const float4* wpack = (const float4*)(ws_c + WS_WPACK);
    int t = threadIdx.x;
    int row0 = blockIdx.x * 16;

    for (int idx = t; idx < 16 * IN_F; idx += 256) {
        int r = idx / IN_F, i = idx - r * IN_F;
        float x = x_seq[(row0 + r) * IN_F + i];
        float sl = x * fast_rcp(1.0f + exp2f(-1.4426950408889634f * x));
        xs_lds[idx] = make_float2(x, sl);
    }
    __syncthreads();

    int o = t & 63, grp = t >> 6;
    const float2* xr0 = xs_lds + (grp * 4 + 0) * IN_F;
    const float2* xr1 = xs_lds + (grp * 4 + 1) * IN_F;
    const float2* xr2 = xs_lds + (grp * 4 + 2) * IN_F;
    const float2* xr3 = xs_lds + (grp * 4 + 3) * IN_F;
    float acc0 = 0.f, acc1 = 0.f, acc2 = 0.f, acc3 = 0.f;
    const float NEG_HALF_LOG2E = -0.7213475204444817f;

    for (int i = 0; i < IN_F; ++i) {
        float4 wp = wpack[i * 64 + o];
        {
            float2 xs = xr0[i];
            float xsc = fmaf(xs.x, wp.x, wp.y); float u = xsc * xsc;
            float e = exp2f(u * NEG_HALF_LOG2E);
            acc0 = fmaf((u - 1.0f) * e, wp.z, acc0);
            acc0 = fmaf(xs.y, wp.w, acc0);
        }
        {
            float2 xs = xr1[i];
            float xsc = fmaf(xs.x, wp.x, wp.y); float u = xsc * xsc;
            float e = exp2f(u * NEG_HALF_LOG2E);
            acc1 = fmaf((u - 1.0f) * e, wp.z, acc1);
            acc1 = fmaf(xs.y, wp.w, acc1);
        }
        {
            float2 xs = xr2[i];
            float xsc = fmaf(xs.x, wp.x, wp.y); float u = xsc * xsc;
            float e = exp2f(u * NEG_HALF_LOG2E);
            acc2 = fmaf((u - 1.0f) * e, wp.z, acc2);
            acc2 = fmaf(xs.y, wp.w, acc2);
        }
        {
            float2 xs = xr3[i];
            float xsc = fmaf(xs.x, wp.x, wp.y); float u = xsc * xsc;
            float e = exp2f(u * NEG_HALF_LOG2E);
            acc3 = fmaf((u - 1.0f) * e, wp.z, acc3);
            acc3 = fmaf(xs.y, wp.w, acc3);
        }
    }

    // BatchNorm (eval)
    float bscale = bn_g[o] * fast_rsq(bn_v[o] + 1e-5f);
    float bshift = fmaf(-bn_m[o], bscale, bn_b[o]);
    float lg = ln_g[o], lb = ln_b[o];
    float vals[4] = {acc0, acc1, acc2, acc3};
    #pragma unroll
    for (int rr = 0; rr < 4; ++rr) {
        float y = fmaf(vals[rr], bscale, bshift);
        // LayerNorm across 64 lanes (= o dim)
        float s = y;
        #pragma unroll
        for (int m = 1; m < 64; m <<= 1) s += __shfl_xor(s, m, 64);
        float mu = s * (1.0f / 64.0f);
        float d = y - mu;
        float s2 = d * d;
        #pragma unroll
        for (int m = 1; m < 64; m <<= 1) s2 += __shfl_xor(s2, m, 64);
        float rstd = fast_rsq(s2 * (1.0f / 64.0f) + 1e-5f);
        x_emb[(row0 + grp * 4 + rr) * 64 + o] = fmaf(d * rstd, lg, lb);
    }
}

// ---------------- K2: gi = x_emb @ w_ih^T + b_ih (both directions) ----------------
// block = 384 thr (thread = gate g incl dir), 16 rows/block, x-row loads wave-uniform.
__global__ __launch_bounds__(384) void gi_kernel(
    const float* __restrict__ ws_c,
    const float* __restrict__ bihf, const float* __restrict__ bihb,
    float* __restrict__ gi) {
    const float4* wT4   = (const float4*)(ws_c + WS_WT4);
    const float*  x_emb = ws_c + WS_XEMB;
    int g = threadIdx.x;
    int dir = g / 192, gg = g - dir * 192;
    float bih = dir ? bihb[gg] : bihf[gg];
    float4 w[16];
    #pragma unroll
    for (int k4 = 0; k4 < 16; ++k4) w[k4] = wT4[k4 * 384 + g];
    int n0 = blockIdx.x * 16;
    for (int rr = 0; rr < 16; ++rr) {
        int n = n0 + rr;                       // wave-uniform -> s_load path
        const float4* xr = (const float4*)(x_emb + n * 64);
        float acc = bih;
        #pragma unroll
        for (int k4 = 0; k4 < 16; ++k4) {
            float4 xv = xr[k4]; float4 wv = w[k4];
            acc = fmaf(xv.x, wv.x, acc); acc = fmaf(xv.y, wv.y, acc);
            acc = fmaf(xv.z, wv.z, acc); acc = fmaf(xv.w, wv.w, acc);
        }
        gi[n * 384 + g] = acc;
    }
}

// ---------------- K3: bidirectional GRU recurrence ----------------
// 128 blocks = (b, dir); 192 threads = gate rows; w_hh row in registers; h via LDS broadcast.
__global__ __launch_bounds__(192) void gru_kernel(
    const float* __restrict__ ws_c,
    const float* __restrict__ whhf, const float* __restrict__ bhhf,
    const float* __restrict__ whhb, const float* __restrict__ bhhb,
    float* __restrict__ hc) {
    __shared__ __align__(16) float h_lds[64];
    __shared__ float gh_buf[192];
    const float* gi = ws_c + WS_GI;
    int t = threadIdx.x;
    int b = blockIdx.x & 63, dir = blockIdx.x >> 6;
    const float* whh = dir ? whhb : whhf;
    const float* bhh = dir ? bhhb : bhhf;
    float4 w[16];
    const float4* wrow = (const float4*)(whh + t * 64);
    #pragma unroll
    for (int q = 0; q < 16; ++q) w[q] = wrow[q];
    float bias = bhh[t];
    if (t < 64) h_lds[t] = 0.0f;
    float hreg = 0.0f;
    __syncthreads();

    for (int ss = 0; ss < SEQ; ++ss) {
        int sidx = dir ? (SEQ - 1 - ss) : ss;
        int base = (b * SEQ + sidx) * 384 + dir * 192;
        float ir = 0.f, iz = 0.f, in_ = 0.f;
        if (t < 64) {   // whole wave 0, no divergence; issued before dot to hide latency
            ir  = gi[base + t];
            iz  = gi[base + 64 + t];
            in_ = gi[base + 128 + t];
        }
        float a0 = 0.f, a1 = 0.f, a2 = 0.f, a3 = 0.f;
        const float4* h4 = (const float4*)h_lds;
        #pragma unroll
        for (int q = 0; q < 16; ++q) {
            float4 hv = h4[q]; float4 wv = w[q];
            a0 = fmaf(hv.x, wv.x, a0); a1 = fmaf(hv.y, wv.y, a1);
            a2 = fmaf(hv.z, wv.z, a2); a3 = fmaf(hv.w, wv.w, a3);
        }
        gh_buf[t] = bias + ((a0 + a1) + (a2 + a3));
        __syncthreads();
        if (t < 64) {
            float r = sigmoid_(ir + gh_buf[t]);
            float z = sigmoid_(iz + gh_buf[64 + t]);
            float n = tanh_(fmaf(r, gh_buf[128 + t], in_));
            hreg = fmaf(z, hreg - n, n);       // (1-z)*n + z*h
            h_lds[t] = hreg;
        }
        __syncthreads();
    }
    if (t < 64) hc[b * 128 + dir * 64 + t] = hreg;
}

// ---------------- K4: classifier head ----------------
__global__ __launch_bounds__(256) void head_kernel(
    const float* __restrict__ ws_c,
    const float* __restrict__ fc1w, const float* __restrict__ fc1b,
    const float* __restrict__ fc2w, const float* __restrict__ fc2b,
    float* __restrict__ out) {
    __shared__ float hc_l[64 * 128];
    __shared__ float h1_l[64 * 64];
    const float* hc = ws_c + WS_HC;
    int t = threadIdx.x;
    for (int idx = t; idx < 8192; idx += 256) hc_l[idx] = hc[idx];
    __syncthreads();
    for (int oidx = t; oidx < 4096; oidx += 256) {
        int bb = oidx >> 6, jj = oidx & 63;
        float acc = fc1b[jj];
        const float* hr = hc_l + bb * 128;
        const float* wr = fc1w + jj * 128;
        #pragma unroll 4
        for (int k = 0; k < 128; ++k) acc = fmaf(hr[k], wr[k], acc);
        h1_l[bb * 64 + jj] = fmaxf(acc, 0.0f);
    }
    __syncthreads();
    for (int oidx = t; oidx < BATCH * NCLS; oidx += 256) {
        int bb = oidx / NCLS, c = oidx - bb * NCLS;
        float acc = fc2b[c];
        const float* hr = h1_l + bb * 64;
        const float* wr = fc2w + c * 64;
        #pragma unroll 4
        for (int k = 0; k < 64; ++k) acc = fmaf(hr[k], wr[k], acc);
        out[bb * NCLS + c] = acc;
    }
}

extern "C" void kernel_launch(void* const* d_in, const int* in_sizes, int n_in,
                              void* d_out, int out_size, void* d_ws, size_t ws_size,
                              hipStream_t stream) {
    const float* x_seq = (const float*)d_in[0];
    const float* wscal = (const float*)d_in[1];
    const float* wtran = (const float*)d_in[2];
    const float* wwght = (const float*)d_in[3];
    const float* bwght = (const float*)d_in[4];
    const float* bn_g  = (const float*)d_in[5];
    const float* bn_b  = (const float*)d_in[6];
    const float* bn_m  = (const float*)d_in[7];
    const float* bn_v  = (const float*)d_in[8];
    const float* ln_g  = (const float*)d_in[9];
    const float* ln_b  = (const float*)d_in[10];
    const float* wihf  = (const float*)d_in[11];
    const float* whhf  = (const float*)d_in[12];
    const float* bihf  = (const float*)d_in[13];
    const float* bhhf  = (const float*)d_in[14];
    const float* wihb  = (const float*)d_in[15];
    const float* whhb  = (const float*)d_in[16];
    const float* bihb  = (const float*)d_in[17];
    const float* bhhb  = (const float*)d_in[18];
    const float* fc1w  = (const float*)d_in[19];
    const float* fc1b  = (const float*)d_in[20];
    const float* fc2w  = (const float*)d_in[21];
    const float* fc2b  = (const float*)d_in[22];
    float* ws  = (float*)d_ws;
    float* out = (float*)d_out;

    hipLaunchKernelGGL(prep_kernel, dim3(186), dim3(256), 0, stream,
                       wscal, wtran, wwght, bwght, wihf, wihb, ws);
    hipLaunchKernelGGL(wavkan_kernel, dim3(NROWS / 16), dim3(256), 0, stream,
                       x_seq, bn_g, bn_b, bn_m, bn_v, ln_g, ln_b, ws, ws + WS_XEMB);
    hipLaunchKernelGGL(gi_kernel, dim3(NROWS / 16), dim3(384), 0, stream,
                       ws, bihf, bihb, ws + WS_GI);
    hipLaunchKernelGGL(gru_kernel, dim3(128), dim3(192), 0, stream,
                       ws, whhf, bhhf, whhb, bhhb, ws + WS_HC);
    hipLaunchKernelGGL(head_kernel, dim3(1), dim3(256), 0, stream,
                       ws, fc1w, fc1b, fc2w, fc2b, out);
}

// Round 2
// 257.229 us; speedup vs baseline: 1.3919x; 1.3919x over previous
//
#include <hip/hip_runtime.h>

#define IN_F   360
#define HIDN   64
#define NCLS   5
#define BATCH  64
#define SEQ    128
#define NROWS  (BATCH*SEQ)   // 8192

// workspace layout (float offsets)
#define WS_FLAG  0            // int flag: 0 => scale==1 && trans==0 everywhere (fast path ok)
#define WS_WPACK 16           // float4[360*64] = 92160 floats (general path)
#define WS_WFAST 92176        // float2[360*64] = 46080 floats (fast path packed {C*ww, bw})
#define WS_WT4   138256       // 24576 floats (w_ih transposed, float4-packed)
#define WS_XEMB  162832       // 8192*64 = 524288
#define WS_GI    687120       // 8192*384 = 3145728
#define WS_HC    3832848      // 64*128 = 8192
// total ~3.84M floats = 15.4 MB

#define LOG2E        1.4426950408889634f
#define NEG_HALF_L2E (-0.7213475204444817f)

__device__ __forceinline__ float fast_rcp(float x) { return __builtin_amdgcn_rcpf(x); }
__device__ __forceinline__ float fast_rsq(float x) { return __builtin_amdgcn_rsqf(x); }
__device__ __forceinline__ float sigmoid_(float x) {
    x = fminf(fmaxf(x, -60.0f), 60.0f);
    return fast_rcp(1.0f + exp2f(-LOG2E * x));
}
__device__ __forceinline__ float tanh_(float x) {
    x = fminf(fmaxf(x, -30.0f), 30.0f);
    float e = exp2f(-2.8853900817779268f * x);   // e^{-2x}
    return (1.0f - e) * fast_rcp(1.0f + e);
}

// ---------------- K0: weight prep + fast-path eligibility check ----------------
__global__ __launch_bounds__(256) void prep_kernel(
    const float* __restrict__ scale, const float* __restrict__ trans,
    const float* __restrict__ ww,    const float* __restrict__ bw,
    const float* __restrict__ wihf,  const float* __restrict__ wihb,
    float* __restrict__ ws) {
    int idx = blockIdx.x * 256 + threadIdx.x;
    float4* wpack  = (float4*)(ws + WS_WPACK);
    float2* wfast2 = (float2*)(ws + WS_WFAST);
    float*  wT4    = ws + WS_WT4;
    int*    flagp  = (int*)(ws + WS_FLAG);
    if (idx < 64 * IN_F) {
        int o = idx & 63, i = idx >> 6;
        float s  = scale[o * IN_F + i];
        float tr = trans[o * IN_F + i];
        if (s != 1.0f || tr != 0.0f) atomicOr(flagp, 1);
        float a  = 1.0f / s;
        float b  = -tr * a;
        float wq = 0.8673250705840776f * ww[o * IN_F + i];   // 2/(sqrt(3)*pi^0.25)
        float bb = bw[o * IN_F + i];
        wpack[i * 64 + o] = make_float4(a, b, wq, bb);
        // fast-path layout: float4 j4 = i2*64+o holds {Cw(2i2),bw(2i2),Cw(2i2+1),bw(2i2+1)}
        wfast2[(i >> 1) * 128 + o * 2 + (i & 1)] = make_float2(wq, bb);
    }
    int idx2 = idx - 64 * IN_F;
    if (idx2 >= 0 && idx2 < 24576) {
        int e = idx2 & 3; int rest = idx2 >> 2;
        int g = rest % 384; int k4 = rest / 384;
        int k = k4 * 4 + e; int dir = g / 192; int gg = g - dir * 192;
        const float* src = dir ? wihb : wihf;
        wT4[idx2] = src[gg * 64 + k];
    }
}

// ---------------- K1: WavKAN + BatchNorm + LayerNorm ----------------
// block = 256 thr (4 waves), 16 rows/block. lane = o, wave grp owns 4 rows.
__global__ __launch_bounds__(256) void wavkan_kernel(
    const float* __restrict__ x_seq,
    const float* __restrict__ bn_g, const float* __restrict__ bn_b,
    const float* __restrict__ bn_m, const float* __restrict__ bn_v,
    const float* __restrict__ ln_g, const float* __restrict__ ln_b,
    const float* __restrict__ ws_c, float* __restrict__ x_emb) {
    __shared__ float2 xs_lds[16 * IN_F];   // 46 KB
    int t = threadIdx.x;
    int row0 = blockIdx.x * 16;
    int o = t & 63, grp = t >> 6;
    int fast = (*(const int*)(ws_c + WS_FLAG)) == 0;

    float acc0 = 0.f, acc1 = 0.f, acc2 = 0.f, acc3 = 0.f;

    if (fast) {
        // scale==1, trans==0: x_scaled = x, o-independent -> K=720 GEMM.
        for (int idx = t; idx < 16 * IN_F; idx += 256) {
            int r = idx / IN_F, i = idx - r * IN_F;
            float x = x_seq[(row0 + r) * IN_F + i];
            float u = x * x;
            float phi = (u - 1.0f) * exp2f(u * NEG_HALF_L2E);      // C folded into weights
            float sl  = x * fast_rcp(1.0f + exp2f(-LOG2E * x));
            xs_lds[idx] = make_float2(phi, sl);
        }
        __syncthreads();
        const float4* wf4 = (const float4*)(ws_c + WS_WFAST);
        const float4* xs4 = (const float4*)xs_lds;
        const float4* xr0 = xs4 + (grp * 4 + 0) * 180;
        const float4* xr1 = xs4 + (grp * 4 + 1) * 180;
        const float4* xr2 = xs4 + (grp * 4 + 2) * 180;
        const float4* xr3 = xs4 + (grp * 4 + 3) * 180;
        #pragma unroll 2
        for (int i2 = 0; i2 < 180; ++i2) {
            float4 wp = wf4[i2 * 64 + o];
            float4 a = xr0[i2];
            acc0 = fmaf(a.x, wp.x, acc0); acc0 = fmaf(a.y, wp.y, acc0);
            acc0 = fmaf(a.z, wp.z, acc0); acc0 = fmaf(a.w, wp.w, acc0);
            float4 b = xr1[i2];
            acc1 = fmaf(b.x, wp.x, acc1); acc1 = fmaf(b.y, wp.y, acc1);
            acc1 = fmaf(b.z, wp.z, acc1); acc1 = fmaf(b.w, wp.w, acc1);
            float4 c = xr2[i2];
            acc2 = fmaf(c.x, wp.x, acc2); acc2 = fmaf(c.y, wp.y, acc2);
            acc2 = fmaf(c.z, wp.z, acc2); acc2 = fmaf(c.w, wp.w, acc2);
            float4 d = xr3[i2];
            acc3 = fmaf(d.x, wp.x, acc3); acc3 = fmaf(d.y, wp.y, acc3);
            acc3 = fmaf(d.z, wp.z, acc3); acc3 = fmaf(d.w, wp.w, acc3);
        }
    } else {
        // general path (per-(o,i) scale/translation)
        for (int idx = t; idx < 16 * IN_F; idx += 256) {
            int r = idx / IN_F, i = idx - r * IN_F;
            float x = x_seq[(row0 + r) * IN_F + i];
            float sl = x * fast_rcp(1.0f + exp2f(-LOG2E * x));
            xs_lds[idx] = make_float2(x, sl);
        }
        __syncthreads();
        const float4* wpack = (const float4*)(ws_c + WS_WPACK);
        const float2* xr0 = xs_lds + (grp * 4 + 0) * IN_F;
        const float2* xr1 = xs_lds + (grp * 4 + 1) * IN_F;
        const float2* xr2 = xs_lds + (grp * 4 + 2) * IN_F;
        const float2* xr3 = xs_lds + (grp * 4 + 3) * IN_F;
        for (int i = 0; i < IN_F; ++i) {
            float4 wp = wpack[i * 64 + o];
            {
                float2 xs = xr0[i];
                float xsc = fmaf(xs.x, wp.x, wp.y); float u = xsc * xsc;
                float e = exp2f(u * NEG_HALF_L2E);
                acc0 = fmaf((u - 1.0f) * e, wp.z, acc0);
                acc0 = fmaf(xs.y, wp.w, acc0);
            }
            {
                float2 xs = xr1[i];
                float xsc = fmaf(xs.x, wp.x, wp.y); float u = xsc * xsc;
                float e = exp2f(u * NEG_HALF_L2E);
                acc1 = fmaf((u - 1.0f) * e, wp.z, acc1);
                acc1 = fmaf(xs.y, wp.w, acc1);
            }
            {
                float2 xs = xr2[i];
                float xsc = fmaf(xs.x, wp.x, wp.y); float u = xsc * xsc;
                float e = exp2f(u * NEG_HALF_L2E);
                acc2 = fmaf((u - 1.0f) * e, wp.z, acc2);
                acc2 = fmaf(xs.y, wp.w, acc2);
            }
            {
                float2 xs = xr3[i];
                float xsc = fmaf(xs.x, wp.x, wp.y); float u = xsc * xsc;
                float e = exp2f(u * NEG_HALF_L2E);
                acc3 = fmaf((u - 1.0f) * e, wp.z, acc3);
                acc3 = fmaf(xs.y, wp.w, acc3);
            }
        }
    }

    // BatchNorm (eval) + LayerNorm across o (the 64 lanes)
    float bscale = bn_g[o] * fast_rsq(bn_v[o] + 1e-5f);
    float bshift = fmaf(-bn_m[o], bscale, bn_b[o]);
    float lg = ln_g[o], lb = ln_b[o];
    float vals[4] = {acc0, acc1, acc2, acc3};
    #pragma unroll
    for (int rr = 0; rr < 4; ++rr) {
        float y = fmaf(vals[rr], bscale, bshift);
        float s = y;
        #pragma unroll
        for (int m = 1; m < 64; m <<= 1) s += __shfl_xor(s, m, 64);
        float mu = s * (1.0f / 64.0f);
        float d = y - mu;
        float s2 = d * d;
        #pragma unroll
        for (int m = 1; m < 64; m <<= 1) s2 += __shfl_xor(s2, m, 64);
        float rstd = fast_rsq(s2 * (1.0f / 64.0f) + 1e-5f);
        x_emb[(row0 + grp * 4 + rr) * 64 + o] = fmaf(d * rstd, lg, lb);
    }
}

// ---------------- K2: gi = x_emb @ w_ih^T + b_ih (both directions) ----------------
__global__ __launch_bounds__(384) void gi_kernel(
    const float* __restrict__ ws_c,
    const float* __restrict__ bihf, const float* __restrict__ bihb,
    float* __restrict__ gi) {
    const float4* wT4   = (const float4*)(ws_c + WS_WT4);
    const float*  x_emb = ws_c + WS_XEMB;
    int g = threadIdx.x;
    int dir = g / 192, gg = g - dir * 192;
    float bih = dir ? bihb[gg] : bihf[gg];
    float4 w[16];
    #pragma unroll
    for (int k4 = 0; k4 < 16; ++k4) w[k4] = wT4[k4 * 384 + g];
    int n0 = blockIdx.x * 16;
    for (int rr = 0; rr < 16; ++rr) {
        int n = n0 + rr;                       // wave-uniform -> scalar-load path
        const float4* xr = (const float4*)(x_emb + n * 64);
        float acc = bih;
        #pragma unroll
        for (int k4 = 0; k4 < 16; ++k4) {
            float4 xv = xr[k4]; float4 wv = w[k4];
            acc = fmaf(xv.x, wv.x, acc); acc = fmaf(xv.y, wv.y, acc);
            acc = fmaf(xv.z, wv.z, acc); acc = fmaf(xv.w, wv.w, acc);
        }
        gi[n * 384 + g] = acc;
    }
}

// ---------------- K3: bidirectional GRU recurrence ----------------
// 128 blocks = (b,dir); 192 threads = gate rows. One barrier/step:
// per-wave private h copy + double-buffered gh; gi prefetched one step ahead.
__global__ __launch_bounds__(192) void gru_kernel(
    const float* __restrict__ ws_c,
    const float* __restrict__ whhf, const float* __restrict__ bhhf,
    const float* __restrict__ whhb, const float* __restrict__ bhhb,
    float* __restrict__ hc) {
    __shared__ __align__(16) float h_lds[3][64];
    __shared__ float gh[2][192];
    const float* gi = ws_c + WS_GI;
    int t = threadIdx.x, wave = t >> 6, lane = t & 63;
    int b = blockIdx.x & 63, dir = blockIdx.x >> 6;
    const float* whh = dir ? whhb : whhf;
    const float* bhh = dir ? bhhb : bhhf;
    float4 w[16];
    const float4* wrow = (const float4*)(whh + t * 64);
    #pragma unroll
    for (int q = 0; q < 16; ++q) w[q] = wrow[q];
    float bias = bhh[t];
    h_lds[wave][lane] = 0.0f;
    float hreg = 0.0f;

    int s0 = dir ? (SEQ - 1) : 0;
    int base0 = (b * SEQ + s0) * 384 + dir * 192;
    float ir  = gi[base0 + lane];
    float iz  = gi[base0 + 64 + lane];
    float in_ = gi[base0 + 128 + lane];
    __syncthreads();

    for (int ss = 0; ss < SEQ; ++ss) {
        float nir = 0.f, niz = 0.f, nin = 0.f;
        if (ss < SEQ - 1) {
            int s2 = dir ? (SEQ - 2 - ss) : (ss + 1);
            int base = (b * SEQ + s2) * 384 + dir * 192;
            nir = gi[base + lane];
            niz = gi[base + 64 + lane];
            nin = gi[base + 128 + lane];
        }
        const float4* h4 = (const float4*)h_lds[wave];
        float a0 = 0.f, a1 = 0.f, a2 = 0.f, a3 = 0.f;
        #pragma unroll
        for (int q = 0; q < 16; ++q) {
            float4 hv = h4[q]; float4 wv = w[q];
            a0 = fmaf(hv.x, wv.x, a0); a1 = fmaf(hv.y, wv.y, a1);
            a2 = fmaf(hv.z, wv.z, a2); a3 = fmaf(hv.w, wv.w, a3);
        }
        int p = ss & 1;
        gh[p][t] = bias + ((a0 + a1) + (a2 + a3));
        __syncthreads();
        float ghr = gh[p][lane], ghz = gh[p][64 + lane], ghn = gh[p][128 + lane];
        float r = sigmoid_(ir + ghr);
        float z = sigmoid_(iz + ghz);
        float n = tanh_(fmaf(r, ghn, in_));
        hreg = fmaf(z, hreg - n, n);           // (1-z)*n + z*h, identical in all waves
        h_lds[wave][lane] = hreg;
        ir = nir; iz = niz; in_ = nin;
    }
    if (t < 64) hc[b * 128 + dir * 64 + lane] = hreg;
}

// ---------------- K4: classifier head ----------------
// 64 blocks (one per batch row) x 64 lanes.
__global__ __launch_bounds__(64) void head_kernel(
    const float* __restrict__ ws_c,
    const float* __restrict__ fc1w, const float* __restrict__ fc1b,
    const float* __restrict__ fc2w, const float* __restrict__ fc2b,
    float* __restrict__ out) {
    __shared__ __align__(16) float hr[128];
    __shared__ float h1[64];
    const float* hc = ws_c + WS_HC;
    int bb = blockIdx.x, t = threadIdx.x;
    hr[t]      = hc[bb * 128 + t];
    hr[64 + t] = hc[bb * 128 + 64 + t];
    __syncthreads();
    float acc = fc1b[t];
    const float4* w4 = (const float4*)(fc1w + t * 128);
    const float4* h4 = (const float4*)hr;
    #pragma unroll 8
    for (int k4 = 0; k4 < 32; ++k4) {
        float4 wv = w4[k4]; float4 hv = h4[k4];
        acc = fmaf(hv.x, wv.x, acc); acc = fmaf(hv.y, wv.y, acc);
        acc = fmaf(hv.z, wv.z, acc); acc = fmaf(hv.w, wv.w, acc);
    }
    h1[t] = fmaxf(acc, 0.0f);
    __syncthreads();
    if (t < NCLS) {
        float acc2 = fc2b[t];
        const float* wr = fc2w + t * 64;
        #pragma unroll 8
        for (int k = 0; k < 64; ++k) acc2 = fmaf(h1[k], wr[k], acc2);
        out[bb * NCLS + t] = acc2;
    }
}

extern "C" void kernel_launch(void* const* d_in, const int* in_sizes, int n_in,
                              void* d_out, int out_size, void* d_ws, size_t ws_size,
                              hipStream_t stream) {
    const float* x_seq = (const float*)d_in[0];
    const float* wscal = (const float*)d_in[1];
    const float* wtran = (const float*)d_in[2];
    const float* wwght = (const float*)d_in[3];
    const float* bwght = (const float*)d_in[4];
    const float* bn_g  = (const float*)d_in[5];
    const float* bn_b  = (const float*)d_in[6];
    const float* bn_m  = (const float*)d_in[7];
    const float* bn_v  = (const float*)d_in[8];
    const float* ln_g  = (const float*)d_in[9];
    const float* ln_b  = (const float*)d_in[10];
    const float* wihf  = (const float*)d_in[11];
    const float* whhf  = (const float*)d_in[12];
    const float* bihf  = (const float*)d_in[13];
    const float* bhhf  = (const float*)d_in[14];
    const float* wihb  = (const float*)d_in[15];
    const float* whhb  = (const float*)d_in[16];
    const float* bihb  = (const float*)d_in[17];
    const float* bhhb  = (const float*)d_in[18];
    const float* fc1w  = (const float*)d_in[19];
    const float* fc1b  = (const float*)d_in[20];
    const float* fc2w  = (const float*)d_in[21];
    const float* fc2b  = (const float*)d_in[22];
    float* ws  = (float*)d_ws;
    float* out = (float*)d_out;

    hipMemsetAsync(ws + WS_FLAG, 0, sizeof(int), stream);   // flag=0 (fast ok)
    hipLaunchKernelGGL(prep_kernel, dim3(186), dim3(256), 0, stream,
                       wscal, wtran, wwght, bwght, wihf, wihb, ws);
    hipLaunchKernelGGL(wavkan_kernel, dim3(NROWS / 16), dim3(256), 0, stream,
                       x_seq, bn_g, bn_b, bn_m, bn_v, ln_g, ln_b, ws, ws + WS_XEMB);
    hipLaunchKernelGGL(gi_kernel, dim3(NROWS / 16), dim3(384), 0, stream,
                       ws, bihf, bihb, ws + WS_GI);
    hipLaunchKernelGGL(gru_kernel, dim3(128), dim3(192), 0, stream,
                       ws, whhf, bhhf, whhb, bhhb, ws + WS_HC);
    hipLaunchKernelGGL(head_kernel, dim3(64), dim3(64), 0, stream,
                       ws, fc1w, fc1b, fc2w, fc2b, out);
}